// Round 1
// baseline (259.937 us; speedup 1.0000x reference)
//
#include <hip/hip_runtime.h>
#include <hip/hip_bf16.h>
#include <math.h>

typedef __attribute__((ext_vector_type(8))) short short8;
typedef __attribute__((ext_vector_type(4))) float f32x4;
typedef unsigned short u16;

static __device__ __forceinline__ u16 f2bf(float f) {
  union { float f; unsigned u; } v; v.f = f;
  unsigned r = v.u + 0x7fffu + ((v.u >> 16) & 1u);
  return (u16)(r >> 16);
}

static __device__ __forceinline__ void gload_lds16(const void* g, void* l) {
  __builtin_amdgcn_global_load_lds(
      (const __attribute__((address_space(1))) void*)g,
      (__attribute__((address_space(3))) void*)l, 16, 0, 0);
}

// ---------------- fp32 -> bf16 convert (8 elems/thread) ----------------
__global__ __launch_bounds__(256) void cvt_bf16(const float* __restrict__ in,
                                                u16* __restrict__ out, int n) {
  int i = (blockIdx.x * 256 + threadIdx.x) * 8;
  if (i >= n) return;
  float4 a = *(const float4*)(in + i);
  float4 b = *(const float4*)(in + i + 4);
  uint4 pk;
  pk.x = f2bf(a.x) | ((unsigned)f2bf(a.y) << 16);
  pk.y = f2bf(a.z) | ((unsigned)f2bf(a.w) << 16);
  pk.z = f2bf(b.x) | ((unsigned)f2bf(b.y) << 16);
  pk.w = f2bf(b.z) | ((unsigned)f2bf(b.w) << 16);
  *(uint4*)(out + i) = pk;
}

// -------- transpose fp32 W[KD][ND] -> bf16 WT[ND][KD] (tiled 64x64) --------
template<int KD, int ND>
__global__ __launch_bounds__(256) void transpose_bf16(const float* __restrict__ W,
                                                      u16* __restrict__ WT) {
  __shared__ float tile[64][65];
  const int c0 = blockIdx.x * 64;
  const int k0 = blockIdx.y * 64;
  const int t = threadIdx.x;
  const int lr = t >> 2;
  const int lc = (t & 3) * 16;
  const float* src = W + (size_t)(k0 + lr) * ND + c0 + lc;
#pragma unroll
  for (int i = 0; i < 16; i += 4) {
    float4 v = *(const float4*)(src + i);
    tile[lr][lc + i] = v.x; tile[lr][lc + i + 1] = v.y;
    tile[lr][lc + i + 2] = v.z; tile[lr][lc + i + 3] = v.w;
  }
  __syncthreads();
  unsigned pk[8];
#pragma unroll
  for (int j = 0; j < 8; ++j) {
    u16 lo = f2bf(tile[lc + 2 * j][lr]);
    u16 hi = f2bf(tile[lc + 2 * j + 1][lr]);
    pk[j] = lo | ((unsigned)hi << 16);
  }
  u16* dst = WT + (size_t)(c0 + lr) * KD + k0 + lc;
  *(uint4*)(dst) = make_uint4(pk[0], pk[1], pk[2], pk[3]);
  *(uint4*)(dst + 8) = make_uint4(pk[4], pk[5], pk[6], pk[7]);
}

// -------- GEMM: C[M,N] = A[M,1024] * Bt[N,1024]^T + bias --------
// MODE 0: scatter to q/k/v bf16 buffers [bh][t][64]; MODE 1: fp32 out [M][NSIZE]
template<int NSIZE, int MODE>
__global__ __launch_bounds__(256) void gemm_bt(const u16* __restrict__ A,
                                               const u16* __restrict__ Bt,
                                               const float* __restrict__ bias,
                                               u16* __restrict__ qb,
                                               u16* __restrict__ kb,
                                               u16* __restrict__ vb,
                                               float* __restrict__ outp) {
  constexpr int K = 1024;
  __shared__ u16 As[128 * 64];
  __shared__ u16 Bs[128 * 64];
  const int tid = threadIdx.x;
  const int lane = tid & 63;
  const int wid = tid >> 6;
  const int wm = (wid >> 1) * 64;
  const int wn = (wid & 1) * 64;
  const int row0 = blockIdx.x * 128;
  const int col0 = blockIdx.y * 128;

  f32x4 acc[4][4] = {};

  const u16* ga = A + (size_t)(row0 + (tid >> 3)) * K + (tid & 7) * 8;
  const u16* gb = Bt + (size_t)(col0 + (tid >> 3)) * K + (tid & 7) * 8;
  u16* la = As + tid * 8;
  u16* lb = Bs + tid * 8;

  for (int kt = 0; kt < K / 64; ++kt) {
#pragma unroll
    for (int i = 0; i < 4; ++i) {
      gload_lds16(ga + (size_t)i * 32 * K + kt * 64, la + i * 2048);
      gload_lds16(gb + (size_t)i * 32 * K + kt * 64, lb + i * 2048);
    }
    __syncthreads();
#pragma unroll
    for (int ks = 0; ks < 2; ++ks) {
      short8 af[4], bf[4];
      const int ko = ks * 32 + (lane >> 4) * 8;
#pragma unroll
      for (int mt = 0; mt < 4; ++mt)
        af[mt] = *(const short8*)(As + (wm + mt * 16 + (lane & 15)) * 64 + ko);
#pragma unroll
      for (int nt = 0; nt < 4; ++nt)
        bf[nt] = *(const short8*)(Bs + (wn + nt * 16 + (lane & 15)) * 64 + ko);
#pragma unroll
      for (int mt = 0; mt < 4; ++mt)
#pragma unroll
        for (int nt = 0; nt < 4; ++nt)
          acc[mt][nt] = __builtin_amdgcn_mfma_f32_16x16x32_bf16(af[mt], bf[nt], acc[mt][nt], 0, 0, 0);
    }
    __syncthreads();
  }

#pragma unroll
  for (int nt = 0; nt < 4; ++nt) {
    const int col = col0 + wn + nt * 16 + (lane & 15);
    const float bv = bias[col];
    if (MODE == 0) {
      const int part = col >> 10;
      const int h = (col >> 6) & 15;
      const int d = col & 63;
      u16* dp = part == 0 ? qb : (part == 1 ? kb : vb);
#pragma unroll
      for (int mt = 0; mt < 4; ++mt) {
#pragma unroll
        for (int r = 0; r < 4; ++r) {
          const int row = row0 + wm + mt * 16 + (lane >> 4) * 4 + r;
          const int bidx = row >> 11;
          const int tt = row & 2047;
          dp[((size_t)((bidx << 4) + h) * 2048 + tt) * 64 + d] = f2bf(acc[mt][nt][r] + bv);
        }
      }
    } else {
#pragma unroll
      for (int mt = 0; mt < 4; ++mt) {
#pragma unroll
        for (int r = 0; r < 4; ++r) {
          const int row = row0 + wm + mt * 16 + (lane >> 4) * 4 + r;
          outp[(size_t)row * NSIZE + col] = acc[mt][nt][r] + bv;
        }
      }
    }
  }
}

// -------- flash attention: grid (t/64, b*nh); 4 waves x 16 q-rows --------
__global__ __launch_bounds__(256) void attn_fwd(const u16* __restrict__ Qb,
                                                const u16* __restrict__ Kb,
                                                const u16* __restrict__ Vb,
                                                u16* __restrict__ Yb) {
  __shared__ u16 Ks[64 * 72];
  __shared__ u16 Vt[64 * 72];
  __shared__ u16 Ps[4][16 * 72];
  const int bh = blockIdx.y;
  const int q0 = blockIdx.x * 64;
  const int tid = threadIdx.x;
  const int lane = tid & 63;
  const int wid = tid >> 6;
  const size_t bhbase = (size_t)bh * 2048 * 64;

  short8 qf[2];
  {
    const int qrow = q0 + wid * 16 + (lane & 15);
    const u16* qp = Qb + bhbase + (size_t)qrow * 64 + (lane >> 4) * 8;
    qf[0] = *(const short8*)(qp);
    qf[1] = *(const short8*)(qp + 32);
  }

  f32x4 accy[4] = {};
  float m_run[4] = {-1e30f, -1e30f, -1e30f, -1e30f};
  float l_run[4] = {0.f, 0.f, 0.f, 0.f};

  const int str = tid >> 2;
  const int stc = (tid & 3) * 16;
  const int nkv = (q0 >> 6) + 1;

  for (int kv = 0; kv < nkv; ++kv) {
    const int kv0 = kv * 64;
    {
      const u16* ksrc = Kb + bhbase + (size_t)(kv0 + str) * 64 + stc;
      uint4 k0v = *(const uint4*)(ksrc);
      uint4 k1v = *(const uint4*)(ksrc + 8);
      *(uint4*)(&Ks[str * 72 + stc]) = k0v;
      *(uint4*)(&Ks[str * 72 + stc + 8]) = k1v;
      const u16* vsrc = Vb + bhbase + (size_t)(kv0 + str) * 64 + stc;
      union { uint4 v; u16 u[8]; } w0, w1;
      w0.v = *(const uint4*)(vsrc);
      w1.v = *(const uint4*)(vsrc + 8);
#pragma unroll
      for (int i = 0; i < 8; ++i) Vt[(stc + i) * 72 + str] = w0.u[i];
#pragma unroll
      for (int i = 0; i < 8; ++i) Vt[(stc + 8 + i) * 72 + str] = w1.u[i];
    }
    __syncthreads();

    f32x4 s[4];
#pragma unroll
    for (int nt = 0; nt < 4; ++nt) {
      f32x4 z = {};
#pragma unroll
      for (int ks = 0; ks < 2; ++ks) {
        short8 kf = *(const short8*)(&Ks[((lane & 15) + nt * 16) * 72 + ks * 32 + (lane >> 4) * 8]);
        z = __builtin_amdgcn_mfma_f32_16x16x32_bf16(qf[ks], kf, z, 0, 0, 0);
      }
      s[nt] = z;
    }

    const int rowb = q0 + wid * 16 + (lane >> 4) * 4;
#pragma unroll
    for (int nt = 0; nt < 4; ++nt) {
      const int colg = kv0 + nt * 16 + (lane & 15);
#pragma unroll
      for (int r = 0; r < 4; ++r) {
        float v = s[nt][r] * 0.125f;
        s[nt][r] = (colg > rowb + r) ? -1e9f : v;
      }
    }

#pragma unroll
    for (int r = 0; r < 4; ++r) {
      float mx = fmaxf(fmaxf(s[0][r], s[1][r]), fmaxf(s[2][r], s[3][r]));
      mx = fmaxf(mx, __shfl_xor(mx, 1));
      mx = fmaxf(mx, __shfl_xor(mx, 2));
      mx = fmaxf(mx, __shfl_xor(mx, 4));
      mx = fmaxf(mx, __shfl_xor(mx, 8));
      const float mnew = fmaxf(m_run[r], mx);
      const float alpha = expf(m_run[r] - mnew);
      float ps = 0.f;
#pragma unroll
      for (int nt = 0; nt < 4; ++nt) {
        const float p = expf(s[nt][r] - mnew);
        s[nt][r] = p;
        ps += p;
      }
      ps += __shfl_xor(ps, 1);
      ps += __shfl_xor(ps, 2);
      ps += __shfl_xor(ps, 4);
      ps += __shfl_xor(ps, 8);
      l_run[r] = l_run[r] * alpha + ps;
      m_run[r] = mnew;
#pragma unroll
      for (int nt = 0; nt < 4; ++nt) accy[nt][r] *= alpha;
    }

    u16* P = &Ps[wid][0];
#pragma unroll
    for (int nt = 0; nt < 4; ++nt) {
      const int col = nt * 16 + (lane & 15);
#pragma unroll
      for (int r = 0; r < 4; ++r)
        P[((lane >> 4) * 4 + r) * 72 + col] = f2bf(s[nt][r]);
    }

#pragma unroll
    for (int ks = 0; ks < 2; ++ks) {
      short8 pf = *(const short8*)(&P[(lane & 15) * 72 + ks * 32 + (lane >> 4) * 8]);
#pragma unroll
      for (int nt = 0; nt < 4; ++nt) {
        short8 vf = *(const short8*)(&Vt[((lane & 15) + nt * 16) * 72 + ks * 32 + (lane >> 4) * 8]);
        accy[nt] = __builtin_amdgcn_mfma_f32_16x16x32_bf16(pf, vf, accy[nt], 0, 0, 0);
      }
    }
    __syncthreads();
  }

#pragma unroll
  for (int r = 0; r < 4; ++r) {
    const int row = q0 + wid * 16 + (lane >> 4) * 4 + r;
    const float inv = 1.0f / l_run[r];
    const size_t base = ((size_t)(bh >> 4) * 2048 + row) * 1024 + (bh & 15) * 64;
#pragma unroll
    for (int nt = 0; nt < 4; ++nt)
      Yb[base + nt * 16 + (lane & 15)] = f2bf(accy[nt][r] * inv);
  }
}

extern "C" void kernel_launch(void* const* d_in, const int* in_sizes, int n_in,
                              void* d_out, int out_size, void* d_ws, size_t ws_size,
                              hipStream_t stream) {
  const float* x      = (const float*)d_in[0];
  const float* w_attn = (const float*)d_in[1];
  const float* b_attn = (const float*)d_in[2];
  const float* w_proj = (const float*)d_in[3];
  const float* b_proj = (const float*)d_in[4];
  float* out = (float*)d_out;
  char* ws = (char*)d_ws;

  u16* xb  = (u16*)(ws + (size_t)0);           // 8 MB: x bf16 [4096][1024]
  u16* wTa = (u16*)(ws + ((size_t)8  << 20));  // 6 MB: w_attn^T bf16 [3072][1024]
  u16* wTp = (u16*)(ws + ((size_t)14 << 20));  // 2 MB: w_proj^T bf16 [1024][1024]
  u16* qb  = (u16*)(ws + ((size_t)16 << 20));  // 8 MB: Q [32][2048][64]
  u16* kb  = (u16*)(ws + ((size_t)24 << 20));  // 8 MB: K
  u16* vb  = (u16*)(ws + ((size_t)32 << 20));  // 8 MB: V
  u16* yb  = (u16*)(ws + ((size_t)40 << 20));  // 8 MB: y bf16 [4096][1024]

  cvt_bf16<<<2048, 256, 0, stream>>>(x, xb, 2 * 2048 * 1024);
  transpose_bf16<1024, 3072><<<dim3(48, 16), 256, 0, stream>>>(w_attn, wTa);
  transpose_bf16<1024, 1024><<<dim3(16, 16), 256, 0, stream>>>(w_proj, wTp);
  gemm_bt<3072, 0><<<dim3(32, 24), 256, 0, stream>>>(xb, wTa, b_attn, qb, kb, vb, nullptr);
  attn_fwd<<<dim3(32, 32), 256, 0, stream>>>(qb, kb, vb, yb);
  gemm_bt<1024, 1><<<dim3(32, 8), 256, 0, stream>>>(yb, wTp, b_proj, nullptr, nullptr, nullptr, out);
}

// Round 2
// 151.649 us; speedup vs baseline: 1.7141x; 1.7141x over previous
//
#include <hip/hip_runtime.h>
#include <hip/hip_bf16.h>
#include <math.h>

typedef __attribute__((ext_vector_type(8))) short short8;
typedef __attribute__((ext_vector_type(4))) float f32x4;
typedef unsigned short u16;

static __device__ __forceinline__ u16 f2bf(float f) {
  union { float f; unsigned u; } v; v.f = f;
  unsigned r = v.u + 0x7fffu + ((v.u >> 16) & 1u);
  return (u16)(r >> 16);
}

static __device__ __forceinline__ void gload_lds16(const void* g, void* l) {
  __builtin_amdgcn_global_load_lds(
      (const __attribute__((address_space(1))) void*)g,
      (__attribute__((address_space(3))) void*)l, 16, 0, 0);
}

// ---------------- fp32 -> bf16 convert (8 elems/thread) ----------------
__global__ __launch_bounds__(256) void cvt_bf16(const float* __restrict__ in,
                                                u16* __restrict__ out, int n) {
  int i = (blockIdx.x * 256 + threadIdx.x) * 8;
  if (i >= n) return;
  float4 a = *(const float4*)(in + i);
  float4 b = *(const float4*)(in + i + 4);
  uint4 pk;
  pk.x = f2bf(a.x) | ((unsigned)f2bf(a.y) << 16);
  pk.y = f2bf(a.z) | ((unsigned)f2bf(a.w) << 16);
  pk.z = f2bf(b.x) | ((unsigned)f2bf(b.y) << 16);
  pk.w = f2bf(b.z) | ((unsigned)f2bf(b.w) << 16);
  *(uint4*)(out + i) = pk;
}

// -------- transpose fp32 W[KD][ND] -> bf16 WT[ND][KD] (tiled 64x64) --------
template<int KD, int ND>
__global__ __launch_bounds__(256) void transpose_bf16(const float* __restrict__ W,
                                                      u16* __restrict__ WT) {
  __shared__ float tile[64][65];
  const int c0 = blockIdx.x * 64;
  const int k0 = blockIdx.y * 64;
  const int t = threadIdx.x;
  const int lr = t >> 2;
  const int lc = (t & 3) * 16;
  const float* src = W + (size_t)(k0 + lr) * ND + c0 + lc;
#pragma unroll
  for (int i = 0; i < 16; i += 4) {
    float4 v = *(const float4*)(src + i);
    tile[lr][lc + i] = v.x; tile[lr][lc + i + 1] = v.y;
    tile[lr][lc + i + 2] = v.z; tile[lr][lc + i + 3] = v.w;
  }
  __syncthreads();
  unsigned pk[8];
#pragma unroll
  for (int j = 0; j < 8; ++j) {
    u16 lo = f2bf(tile[lc + 2 * j][lr]);
    u16 hi = f2bf(tile[lc + 2 * j + 1][lr]);
    pk[j] = lo | ((unsigned)hi << 16);
  }
  u16* dst = WT + (size_t)(c0 + lr) * KD + k0 + lc;
  *(uint4*)(dst) = make_uint4(pk[0], pk[1], pk[2], pk[3]);
  *(uint4*)(dst + 8) = make_uint4(pk[4], pk[5], pk[6], pk[7]);
}

// -------- GEMM: C[M,N] = A[M,1024] * Bt[N,1024]^T + bias --------
// MODE 0: scatter to q/k (bf16 [bh][t][64]) and V TRANSPOSED ([bh][d][t]);
// MODE 1: fp32 out [M][NSIZE]
template<int NSIZE, int MODE>
__global__ __launch_bounds__(256) void gemm_bt(const u16* __restrict__ A,
                                               const u16* __restrict__ Bt,
                                               const float* __restrict__ bias,
                                               u16* __restrict__ qb,
                                               u16* __restrict__ kb,
                                               u16* __restrict__ vb,
                                               float* __restrict__ outp) {
  constexpr int K = 1024;
  __shared__ u16 As[128 * 64];
  __shared__ u16 Bs[128 * 64];
  const int tid = threadIdx.x;
  const int lane = tid & 63;
  const int wid = tid >> 6;
  const int wm = (wid >> 1) * 64;
  const int wn = (wid & 1) * 64;
  const int row0 = blockIdx.x * 128;
  const int col0 = blockIdx.y * 128;

  f32x4 acc[4][4] = {};

  const u16* ga = A + (size_t)(row0 + (tid >> 3)) * K + (tid & 7) * 8;
  const u16* gb = Bt + (size_t)(col0 + (tid >> 3)) * K + (tid & 7) * 8;
  u16* la = As + tid * 8;
  u16* lb = Bs + tid * 8;

  for (int kt = 0; kt < K / 64; ++kt) {
#pragma unroll
    for (int i = 0; i < 4; ++i) {
      gload_lds16(ga + (size_t)i * 32 * K + kt * 64, la + i * 2048);
      gload_lds16(gb + (size_t)i * 32 * K + kt * 64, lb + i * 2048);
    }
    __syncthreads();
#pragma unroll
    for (int ks = 0; ks < 2; ++ks) {
      short8 af[4], bf[4];
      const int ko = ks * 32 + (lane >> 4) * 8;
#pragma unroll
      for (int mt = 0; mt < 4; ++mt)
        af[mt] = *(const short8*)(As + (wm + mt * 16 + (lane & 15)) * 64 + ko);
#pragma unroll
      for (int nt = 0; nt < 4; ++nt)
        bf[nt] = *(const short8*)(Bs + (wn + nt * 16 + (lane & 15)) * 64 + ko);
#pragma unroll
      for (int mt = 0; mt < 4; ++mt)
#pragma unroll
        for (int nt = 0; nt < 4; ++nt)
          acc[mt][nt] = __builtin_amdgcn_mfma_f32_16x16x32_bf16(af[mt], bf[nt], acc[mt][nt], 0, 0, 0);
    }
    __syncthreads();
  }

#pragma unroll
  for (int nt = 0; nt < 4; ++nt) {
    const int col = col0 + wn + nt * 16 + (lane & 15);
    const float bv = bias[col];
    if (MODE == 0) {
      const int part = col >> 10;
      const int h = (col >> 6) & 15;
      const int d = col & 63;
      u16* dp = part == 0 ? qb : kb;
#pragma unroll
      for (int mt = 0; mt < 4; ++mt) {
#pragma unroll
        for (int r = 0; r < 4; ++r) {
          const int row = row0 + wm + mt * 16 + (lane >> 4) * 4 + r;
          const int bidx = row >> 11;
          const int tt = row & 2047;
          const u16 val = f2bf(acc[mt][nt][r] + bv);
          if (part == 2)
            vb[((size_t)((bidx << 4) + h) * 64 + d) * 2048 + tt] = val;
          else
            dp[((size_t)((bidx << 4) + h) * 2048 + tt) * 64 + d] = val;
        }
      }
    } else {
#pragma unroll
      for (int mt = 0; mt < 4; ++mt) {
#pragma unroll
        for (int r = 0; r < 4; ++r) {
          const int row = row0 + wm + mt * 16 + (lane >> 4) * 4 + r;
          outp[(size_t)row * NSIZE + col] = acc[mt][nt][r] + bv;
        }
      }
    }
  }
}

// -------- flash attention, load-balanced fold pairing --------
// grid (16, 32): block p handles q-tiles {31-p, p} -> 33 kv-iters per block.
// K staged [t][64], V staged pre-transposed [d][t]; both XOR-swizzled
// (linear LDS dest + inverse-swizzled global src + swizzled read).
__global__ __launch_bounds__(256) void attn_fwd(const u16* __restrict__ Qb,
                                                const u16* __restrict__ Kb,
                                                const u16* __restrict__ Vtb,
                                                u16* __restrict__ Yb) {
  __shared__ u16 Ks[64 * 64];
  __shared__ u16 Vs[64 * 64];
  __shared__ u16 Ps[4][1024];
  const int bh = blockIdx.y;
  const int tid = threadIdx.x;
  const int lane = tid & 63;
  const int wid = tid >> 6;
  const int l15 = lane & 15;
  const int g4 = lane >> 4;
  const size_t bhq = (size_t)bh * 2048 * 64;
  const u16* Kbase = Kb + bhq;
  const u16* Vbase = Vtb + bhq;  // [64 d][2048 t] per bh
  const float C2 = 0.18033688011112042f;  // 0.125 * log2(e)
  u16* Pw = &Ps[wid][0];

#pragma unroll
  for (int ti = 0; ti < 2; ++ti) {
    const int j = (ti == 0) ? (31 - (int)blockIdx.x) : (int)blockIdx.x;
    const int q0 = j * 64;

    short8 qf[2];
    {
      const int qrow = q0 + wid * 16 + l15;
      const u16* qp = Qb + bhq + (size_t)qrow * 64 + g4 * 8;
      qf[0] = *(const short8*)(qp);
      qf[1] = *(const short8*)(qp + 32);
    }
    f32x4 accy[4] = {};
    float m_run[4] = {-1e30f, -1e30f, -1e30f, -1e30f};
    float l_run[4] = {0.f, 0.f, 0.f, 0.f};

    for (int kv = 0; kv <= j; ++kv) {
      const int kv0 = kv * 64;
      // ---- stage K,V tiles (16B chunks, source pre-swizzled) ----
      {
        const u16* kg = Kbase + (size_t)kv0 * 64;
        const u16* vg = Vbase + kv0;
#pragma unroll
        for (int cc = 0; cc < 2; ++cc) {
          const int c = tid + cc * 256;
          const int row = c >> 3;
          const int blk = (c & 7) ^ (row & 7);
          gload_lds16(kg + row * 64 + blk * 8, Ks + c * 8);
          gload_lds16(vg + (size_t)row * 2048 + blk * 8, Vs + c * 8);
        }
      }
      __syncthreads();

      // ---- S = Q K^T (swizzled b128 reads of K rows) ----
      f32x4 s[4];
#pragma unroll
      for (int nt = 0; nt < 4; ++nt) {
        f32x4 z = {};
#pragma unroll
        for (int ks = 0; ks < 2; ++ks) {
          const int R = nt * 16 + l15;
          const int B = ks * 64 + g4 * 16;
          short8 kf = *(const short8*)((const char*)Ks + R * 128 + (B ^ ((R & 7) << 4)));
          z = __builtin_amdgcn_mfma_f32_16x16x32_bf16(qf[ks], kf, z, 0, 0, 0);
        }
        s[nt] = z;
      }

      // ---- causal mask: only on the diagonal tile ----
      if (kv == j) {
        const int rowb = q0 + wid * 16 + g4 * 4;
#pragma unroll
        for (int nt = 0; nt < 4; ++nt) {
          const int colg = kv0 + nt * 16 + l15;
#pragma unroll
          for (int r = 0; r < 4; ++r)
            if (colg > rowb + r) s[nt][r] = -1e30f;
        }
      }

      // ---- online softmax (exp2 domain, raw scores) ----
#pragma unroll
      for (int r = 0; r < 4; ++r) {
        float mx = fmaxf(fmaxf(s[0][r], s[1][r]), fmaxf(s[2][r], s[3][r]));
        mx = fmaxf(mx, __shfl_xor(mx, 1));
        mx = fmaxf(mx, __shfl_xor(mx, 2));
        mx = fmaxf(mx, __shfl_xor(mx, 4));
        mx = fmaxf(mx, __shfl_xor(mx, 8));
        const float mnew = fmaxf(m_run[r], mx);
        const float m2 = mnew * C2;
        const float alpha = __builtin_amdgcn_exp2f(fmaf(m_run[r], C2, -m2));
        float ps = 0.f;
#pragma unroll
        for (int nt = 0; nt < 4; ++nt) {
          const float p = __builtin_amdgcn_exp2f(fmaf(s[nt][r], C2, -m2));
          s[nt][r] = p;
          ps += p;
        }
        ps += __shfl_xor(ps, 1);
        ps += __shfl_xor(ps, 2);
        ps += __shfl_xor(ps, 4);
        ps += __shfl_xor(ps, 8);
        l_run[r] = l_run[r] * alpha + ps;
        m_run[r] = mnew;
#pragma unroll
        for (int nt = 0; nt < 4; ++nt) accy[nt][r] *= alpha;
      }

      // ---- P -> per-wave LDS (swizzled), then PV ----
#pragma unroll
      for (int nt = 0; nt < 4; ++nt) {
        const int colB = (nt * 16 + l15) * 2;
#pragma unroll
        for (int r = 0; r < 4; ++r) {
          const int rowL = g4 * 4 + r;
          *(u16*)((char*)Pw + rowL * 128 + (colB ^ ((rowL & 7) << 4))) = f2bf(s[nt][r]);
        }
      }
#pragma unroll
      for (int ks = 0; ks < 2; ++ks) {
        const int B = ks * 64 + g4 * 16;
        short8 pf = *(const short8*)((const char*)Pw + l15 * 128 + (B ^ ((l15 & 7) << 4)));
#pragma unroll
        for (int nt = 0; nt < 4; ++nt) {
          const int R = nt * 16 + l15;
          short8 vf = *(const short8*)((const char*)Vs + R * 128 + (B ^ ((R & 7) << 4)));
          accy[nt] = __builtin_amdgcn_mfma_f32_16x16x32_bf16(pf, vf, accy[nt], 0, 0, 0);
        }
      }
      __syncthreads();
    }

    // ---- epilogue: normalize, write y [b][t][h*64+d] bf16 ----
#pragma unroll
    for (int r = 0; r < 4; ++r) {
      const int row = q0 + wid * 16 + g4 * 4 + r;
      const float inv = 1.0f / l_run[r];
      const size_t base = ((size_t)(bh >> 4) * 2048 + row) * 1024 + (bh & 15) * 64;
#pragma unroll
      for (int nt = 0; nt < 4; ++nt)
        Yb[base + nt * 16 + l15] = f2bf(accy[nt][r] * inv);
    }
  }
}

extern "C" void kernel_launch(void* const* d_in, const int* in_sizes, int n_in,
                              void* d_out, int out_size, void* d_ws, size_t ws_size,
                              hipStream_t stream) {
  const float* x      = (const float*)d_in[0];
  const float* w_attn = (const float*)d_in[1];
  const float* b_attn = (const float*)d_in[2];
  const float* w_proj = (const float*)d_in[3];
  const float* b_proj = (const float*)d_in[4];
  float* out = (float*)d_out;
  char* ws = (char*)d_ws;

  u16* xb  = (u16*)(ws + (size_t)0);           // 8 MB: x bf16 [4096][1024]
  u16* wTa = (u16*)(ws + ((size_t)8  << 20));  // 6 MB: w_attn^T bf16 [3072][1024]
  u16* wTp = (u16*)(ws + ((size_t)14 << 20));  // 2 MB: w_proj^T bf16 [1024][1024]
  u16* qb  = (u16*)(ws + ((size_t)16 << 20));  // 8 MB: Q [32][2048][64]
  u16* kb  = (u16*)(ws + ((size_t)24 << 20));  // 8 MB: K [32][2048][64]
  u16* vb  = (u16*)(ws + ((size_t)32 << 20));  // 8 MB: V^T [32][64][2048]
  u16* yb  = (u16*)(ws + ((size_t)40 << 20));  // 8 MB: y bf16 [4096][1024]

  cvt_bf16<<<2048, 256, 0, stream>>>(x, xb, 2 * 2048 * 1024);
  transpose_bf16<1024, 3072><<<dim3(48, 16), 256, 0, stream>>>(w_attn, wTa);
  transpose_bf16<1024, 1024><<<dim3(16, 16), 256, 0, stream>>>(w_proj, wTp);
  gemm_bt<3072, 0><<<dim3(32, 24), 256, 0, stream>>>(xb, wTa, b_attn, qb, kb, vb, nullptr);
  attn_fwd<<<dim3(16, 32), 256, 0, stream>>>(qb, kb, vb, yb);
  gemm_bt<1024, 1><<<dim3(32, 8), 256, 0, stream>>>(yb, wTp, b_proj, nullptr, nullptr, nullptr, out);
}

// Round 3
// 151.060 us; speedup vs baseline: 1.7207x; 1.0039x over previous
//
#include <hip/hip_runtime.h>
#include <hip/hip_bf16.h>
#include <math.h>

typedef __attribute__((ext_vector_type(8))) short short8;
typedef __attribute__((ext_vector_type(4))) float f32x4;
typedef unsigned short u16;

static __device__ __forceinline__ u16 f2bf(float f) {
  union { float f; unsigned u; } v; v.f = f;
  unsigned r = v.u + 0x7fffu + ((v.u >> 16) & 1u);
  return (u16)(r >> 16);
}

static __device__ __forceinline__ void gload_lds16(const void* g, void* l) {
  __builtin_amdgcn_global_load_lds(
      (const __attribute__((address_space(1))) void*)g,
      (__attribute__((address_space(3))) void*)l, 16, 0, 0);
}

// ---------------- fp32 -> bf16 convert (8 elems/thread) ----------------
__global__ __launch_bounds__(256) void cvt_bf16(const float* __restrict__ in,
                                                u16* __restrict__ out, int n) {
  int i = (blockIdx.x * 256 + threadIdx.x) * 8;
  if (i >= n) return;
  float4 a = *(const float4*)(in + i);
  float4 b = *(const float4*)(in + i + 4);
  uint4 pk;
  pk.x = f2bf(a.x) | ((unsigned)f2bf(a.y) << 16);
  pk.y = f2bf(a.z) | ((unsigned)f2bf(a.w) << 16);
  pk.z = f2bf(b.x) | ((unsigned)f2bf(b.y) << 16);
  pk.w = f2bf(b.z) | ((unsigned)f2bf(b.w) << 16);
  *(uint4*)(out + i) = pk;
}

// -------- transpose fp32 W[KD][ND] -> bf16 WT[ND][KD] (tiled 64x64) --------
template<int KD, int ND>
__global__ __launch_bounds__(256) void transpose_bf16(const float* __restrict__ W,
                                                      u16* __restrict__ WT) {
  __shared__ float tile[64][65];
  const int c0 = blockIdx.x * 64;
  const int k0 = blockIdx.y * 64;
  const int t = threadIdx.x;
  const int lr = t >> 2;
  const int lc = (t & 3) * 16;
  const float* src = W + (size_t)(k0 + lr) * ND + c0 + lc;
#pragma unroll
  for (int i = 0; i < 16; i += 4) {
    float4 v = *(const float4*)(src + i);
    tile[lr][lc + i] = v.x; tile[lr][lc + i + 1] = v.y;
    tile[lr][lc + i + 2] = v.z; tile[lr][lc + i + 3] = v.w;
  }
  __syncthreads();
  unsigned pk[8];
#pragma unroll
  for (int j = 0; j < 8; ++j) {
    u16 lo = f2bf(tile[lc + 2 * j][lr]);
    u16 hi = f2bf(tile[lc + 2 * j + 1][lr]);
    pk[j] = lo | ((unsigned)hi << 16);
  }
  u16* dst = WT + (size_t)(c0 + lr) * KD + k0 + lc;
  *(uint4*)(dst) = make_uint4(pk[0], pk[1], pk[2], pk[3]);
  *(uint4*)(dst + 8) = make_uint4(pk[4], pk[5], pk[6], pk[7]);
}

// -------- GEMM: C[M,N] = A[M,1024] * Bt[N,1024]^T + bias --------
// MODE 0: scatter to q/k (bf16 [bh][t][64]) and V TRANSPOSED ([bh][d][t]);
// MODE 1: fp32 out [M][NSIZE]
template<int NSIZE, int MODE>
__global__ __launch_bounds__(256) void gemm_bt(const u16* __restrict__ A,
                                               const u16* __restrict__ Bt,
                                               const float* __restrict__ bias,
                                               u16* __restrict__ qb,
                                               u16* __restrict__ kb,
                                               u16* __restrict__ vb,
                                               float* __restrict__ outp) {
  constexpr int K = 1024;
  __shared__ u16 As[128 * 64];
  __shared__ u16 Bs[128 * 64];
  const int tid = threadIdx.x;
  const int lane = tid & 63;
  const int wid = tid >> 6;
  const int wm = (wid >> 1) * 64;
  const int wn = (wid & 1) * 64;
  const int row0 = blockIdx.x * 128;
  const int col0 = blockIdx.y * 128;

  f32x4 acc[4][4] = {};

  const u16* ga = A + (size_t)(row0 + (tid >> 3)) * K + (tid & 7) * 8;
  const u16* gb = Bt + (size_t)(col0 + (tid >> 3)) * K + (tid & 7) * 8;
  u16* la = As + tid * 8;
  u16* lb = Bs + tid * 8;

  for (int kt = 0; kt < K / 64; ++kt) {
#pragma unroll
    for (int i = 0; i < 4; ++i) {
      gload_lds16(ga + (size_t)i * 32 * K + kt * 64, la + i * 2048);
      gload_lds16(gb + (size_t)i * 32 * K + kt * 64, lb + i * 2048);
    }
    __syncthreads();
#pragma unroll
    for (int ks = 0; ks < 2; ++ks) {
      short8 af[4], bf[4];
      const int ko = ks * 32 + (lane >> 4) * 8;
#pragma unroll
      for (int mt = 0; mt < 4; ++mt)
        af[mt] = *(const short8*)(As + (wm + mt * 16 + (lane & 15)) * 64 + ko);
#pragma unroll
      for (int nt = 0; nt < 4; ++nt)
        bf[nt] = *(const short8*)(Bs + (wn + nt * 16 + (lane & 15)) * 64 + ko);
#pragma unroll
      for (int mt = 0; mt < 4; ++mt)
#pragma unroll
        for (int nt = 0; nt < 4; ++nt)
          acc[mt][nt] = __builtin_amdgcn_mfma_f32_16x16x32_bf16(af[mt], bf[nt], acc[mt][nt], 0, 0, 0);
    }
    __syncthreads();
  }

#pragma unroll
  for (int nt = 0; nt < 4; ++nt) {
    const int col = col0 + wn + nt * 16 + (lane & 15);
    const float bv = bias[col];
    if (MODE == 0) {
      const int part = col >> 10;
      const int h = (col >> 6) & 15;
      const int d = col & 63;
      u16* dp = part == 0 ? qb : kb;
#pragma unroll
      for (int mt = 0; mt < 4; ++mt) {
#pragma unroll
        for (int r = 0; r < 4; ++r) {
          const int row = row0 + wm + mt * 16 + (lane >> 4) * 4 + r;
          const int bidx = row >> 11;
          const int tt = row & 2047;
          const u16 val = f2bf(acc[mt][nt][r] + bv);
          if (part == 2)
            vb[((size_t)((bidx << 4) + h) * 64 + d) * 2048 + tt] = val;
          else
            dp[((size_t)((bidx << 4) + h) * 2048 + tt) * 64 + d] = val;
        }
      }
    } else {
#pragma unroll
      for (int mt = 0; mt < 4; ++mt) {
#pragma unroll
        for (int r = 0; r < 4; ++r) {
          const int row = row0 + wm + mt * 16 + (lane >> 4) * 4 + r;
          outp[(size_t)row * NSIZE + col] = acc[mt][nt][r] + bv;
        }
      }
    }
  }
}

// -------- flash attention: 8 waves, 128 q-rows/block, 2-phase pipeline --------
// grid (8, 32): block p handles 128-row q-tiles {15-p, p} -> 34 kv-iters.
// K staged [t][64], V staged pre-transposed [d][t]; both XOR-swizzled
// (linear LDS dest + inverse-swizzled global src + swizzled read).
// Double-buffered staging with raw s_barrier + counted vmcnt (prefetch
// stays in flight across the barrier).
__global__ __launch_bounds__(512) void attn_fwd(const u16* __restrict__ Qb,
                                                const u16* __restrict__ Kb,
                                                const u16* __restrict__ Vtb,
                                                u16* __restrict__ Yb) {
  __shared__ u16 Ks[2][64 * 64];
  __shared__ u16 Vs[2][64 * 64];
  __shared__ u16 Ps[8][1024];
  const int bh = blockIdx.y;
  const int tid = threadIdx.x;
  const int lane = tid & 63;
  const int wid = tid >> 6;
  const int l15 = lane & 15;
  const int g4 = lane >> 4;
  const size_t bhq = (size_t)bh * 2048 * 64;
  const u16* Kbase = Kb + bhq;
  const u16* Vbase = Vtb + bhq;  // [64 d][2048 t] per bh
  const float C2 = 0.18033688011112042f;  // 0.125 * log2(e)
  u16* Pw = &Ps[wid][0];

  // staging geometry (per thread: one 16B K-chunk + one 16B V-chunk)
  const int srow = tid >> 3;                       // 0..63
  const int sblk = (tid & 7) ^ (srow & 7);         // inverse-swizzled source

#pragma unroll
  for (int ti = 0; ti < 2; ++ti) {
    const int T = (ti == 0) ? (15 - (int)blockIdx.x) : (int)blockIdx.x;
    const int q0 = T * 128;
    const int wrow0 = q0 + wid * 16;               // wave's first q-row
    const int nkv = 2 * T + 2;

    short8 qf[2];
    {
      const u16* qp = Qb + bhq + (size_t)(wrow0 + l15) * 64 + g4 * 8;
      qf[0] = *(const short8*)(qp);
      qf[1] = *(const short8*)(qp + 32);
    }
    f32x4 accy[4] = {};
    float m_run[4] = {-1e30f, -1e30f, -1e30f, -1e30f};
    float l_run[4] = {0.f, 0.f, 0.f, 0.f};

    int cur = 0;
    // prologue: stage kv-tile 0 into buf 0
    gload_lds16(Kbase + srow * 64 + sblk * 8, Ks[0] + tid * 8);
    gload_lds16(Vbase + (size_t)srow * 2048 + sblk * 8, Vs[0] + tid * 8);

    for (int kv = 0; kv < nkv; ++kv) {
      const int kv0 = kv * 64;
      if (kv + 1 < nkv) {
        const int nx0 = kv0 + 64;
        gload_lds16(Kbase + (size_t)(nx0 + srow) * 64 + sblk * 8, Ks[cur ^ 1] + tid * 8);
        gload_lds16(Vbase + (size_t)srow * 2048 + nx0 + sblk * 8, Vs[cur ^ 1] + tid * 8);
        asm volatile("s_waitcnt vmcnt(2)" ::: "memory");
      } else {
        asm volatile("s_waitcnt vmcnt(0)" ::: "memory");
      }
      __builtin_amdgcn_s_barrier();
      asm volatile("" ::: "memory");

      if (kv0 <= wrow0 + 15) {  // wave-uniform: skip fully-masked tiles
        const u16* Kt = Ks[cur];
        const u16* Vt = Vs[cur];
        // ---- S = Q K^T (swizzled b128 reads of K rows) ----
        f32x4 s[4];
#pragma unroll
        for (int nt = 0; nt < 4; ++nt) {
          f32x4 z = {};
#pragma unroll
          for (int ks = 0; ks < 2; ++ks) {
            const int R = nt * 16 + l15;
            const int B = ks * 64 + g4 * 16;
            short8 kf = *(const short8*)((const char*)Kt + R * 128 + (B ^ ((R & 7) << 4)));
            z = __builtin_amdgcn_mfma_f32_16x16x32_bf16(qf[ks], kf, z, 0, 0, 0);
          }
          s[nt] = z;
        }

        // ---- causal mask (only tiles straddling the diagonal) ----
        if (kv0 + 63 > wrow0) {
          const int rowb = wrow0 + g4 * 4;
#pragma unroll
          for (int nt = 0; nt < 4; ++nt) {
            const int colg = kv0 + nt * 16 + l15;
#pragma unroll
            for (int r = 0; r < 4; ++r)
              if (colg > rowb + r) s[nt][r] = -1e30f;
          }
        }

        // ---- online softmax (exp2 domain) ----
#pragma unroll
        for (int r = 0; r < 4; ++r) {
          float mx = fmaxf(fmaxf(s[0][r], s[1][r]), fmaxf(s[2][r], s[3][r]));
          mx = fmaxf(mx, __shfl_xor(mx, 1));
          mx = fmaxf(mx, __shfl_xor(mx, 2));
          mx = fmaxf(mx, __shfl_xor(mx, 4));
          mx = fmaxf(mx, __shfl_xor(mx, 8));
          const float mnew = fmaxf(m_run[r], mx);
          const float m2 = mnew * C2;
          const float alpha = __builtin_amdgcn_exp2f(fmaf(m_run[r], C2, -m2));
          float ps = 0.f;
#pragma unroll
          for (int nt = 0; nt < 4; ++nt) {
            const float p = __builtin_amdgcn_exp2f(fmaf(s[nt][r], C2, -m2));
            s[nt][r] = p;
            ps += p;
          }
          ps += __shfl_xor(ps, 1);
          ps += __shfl_xor(ps, 2);
          ps += __shfl_xor(ps, 4);
          ps += __shfl_xor(ps, 8);
          l_run[r] = l_run[r] * alpha + ps;
          m_run[r] = mnew;
#pragma unroll
          for (int nt = 0; nt < 4; ++nt) accy[nt][r] *= alpha;
        }

        // ---- P -> per-wave LDS (swizzled), then PV ----
#pragma unroll
        for (int nt = 0; nt < 4; ++nt) {
          const int colB = (nt * 16 + l15) * 2;
#pragma unroll
          for (int r = 0; r < 4; ++r) {
            const int rowL = g4 * 4 + r;
            *(u16*)((char*)Pw + rowL * 128 + (colB ^ ((rowL & 7) << 4))) = f2bf(s[nt][r]);
          }
        }
#pragma unroll
        for (int ks = 0; ks < 2; ++ks) {
          const int B = ks * 64 + g4 * 16;
          short8 pf = *(const short8*)((const char*)Pw + l15 * 128 + (B ^ ((l15 & 7) << 4)));
#pragma unroll
          for (int nt = 0; nt < 4; ++nt) {
            const int R = nt * 16 + l15;
            short8 vf = *(const short8*)((const char*)Vt + R * 128 + (B ^ ((R & 7) << 4)));
            accy[nt] = __builtin_amdgcn_mfma_f32_16x16x32_bf16(pf, vf, accy[nt], 0, 0, 0);
          }
        }
      }

      asm volatile("" ::: "memory");
      __builtin_amdgcn_s_barrier();
      cur ^= 1;
    }

    // ---- epilogue: normalize, write y [b][t][h*64+d] bf16 ----
#pragma unroll
    for (int r = 0; r < 4; ++r) {
      const int row = wrow0 + g4 * 4 + r;
      const float inv = 1.0f / l_run[r];
      const size_t base = ((size_t)(bh >> 4) * 2048 + row) * 1024 + (bh & 15) * 64;
#pragma unroll
      for (int nt = 0; nt < 4; ++nt)
        Yb[base + nt * 16 + l15] = f2bf(accy[nt][r] * inv);
    }
  }
}

extern "C" void kernel_launch(void* const* d_in, const int* in_sizes, int n_in,
                              void* d_out, int out_size, void* d_ws, size_t ws_size,
                              hipStream_t stream) {
  const float* x      = (const float*)d_in[0];
  const float* w_attn = (const float*)d_in[1];
  const float* b_attn = (const float*)d_in[2];
  const float* w_proj = (const float*)d_in[3];
  const float* b_proj = (const float*)d_in[4];
  float* out = (float*)d_out;
  char* ws = (char*)d_ws;

  u16* xb  = (u16*)(ws + (size_t)0);           // 8 MB: x bf16 [4096][1024]
  u16* wTa = (u16*)(ws + ((size_t)8  << 20));  // 6 MB: w_attn^T bf16 [3072][1024]
  u16* wTp = (u16*)(ws + ((size_t)14 << 20));  // 2 MB: w_proj^T bf16 [1024][1024]
  u16* qb  = (u16*)(ws + ((size_t)16 << 20));  // 8 MB: Q [32][2048][64]
  u16* kb  = (u16*)(ws + ((size_t)24 << 20));  // 8 MB: K [32][2048][64]
  u16* vb  = (u16*)(ws + ((size_t)32 << 20));  // 8 MB: V^T [32][64][2048]
  u16* yb  = (u16*)(ws + ((size_t)40 << 20));  // 8 MB: y bf16 [4096][1024]

  cvt_bf16<<<2048, 256, 0, stream>>>(x, xb, 2 * 2048 * 1024);
  transpose_bf16<1024, 3072><<<dim3(48, 16), 256, 0, stream>>>(w_attn, wTa);
  transpose_bf16<1024, 1024><<<dim3(16, 16), 256, 0, stream>>>(w_proj, wTp);
  gemm_bt<3072, 0><<<dim3(32, 24), 256, 0, stream>>>(xb, wTa, b_attn, qb, kb, vb, nullptr);
  attn_fwd<<<dim3(8, 32), 512, 0, stream>>>(qb, kb, vb, yb);
  gemm_bt<1024, 1><<<dim3(32, 8), 256, 0, stream>>>(yb, wTp, b_proj, nullptr, nullptr, nullptr, out);
}

// Round 4
// 150.344 us; speedup vs baseline: 1.7289x; 1.0048x over previous
//
#include <hip/hip_runtime.h>
#include <hip/hip_bf16.h>
#include <math.h>

typedef __attribute__((ext_vector_type(8))) short short8;
typedef __attribute__((ext_vector_type(4))) float f32x4;
typedef unsigned short u16;

static __device__ __forceinline__ u16 f2bf(float f) {
  union { float f; unsigned u; } v; v.f = f;
  unsigned r = v.u + 0x7fffu + ((v.u >> 16) & 1u);
  return (u16)(r >> 16);
}

static __device__ __forceinline__ void gload_lds16(const void* g, void* l) {
  __builtin_amdgcn_global_load_lds(
      (const __attribute__((address_space(1))) void*)g,
      (__attribute__((address_space(3))) void*)l, 16, 0, 0);
}

// ---------------- fp32 -> bf16 convert (8 elems/thread) ----------------
__global__ __launch_bounds__(256) void cvt_bf16(const float* __restrict__ in,
                                                u16* __restrict__ out, int n) {
  int i = (blockIdx.x * 256 + threadIdx.x) * 8;
  if (i >= n) return;
  float4 a = *(const float4*)(in + i);
  float4 b = *(const float4*)(in + i + 4);
  uint4 pk;
  pk.x = f2bf(a.x) | ((unsigned)f2bf(a.y) << 16);
  pk.y = f2bf(a.z) | ((unsigned)f2bf(a.w) << 16);
  pk.z = f2bf(b.x) | ((unsigned)f2bf(b.y) << 16);
  pk.w = f2bf(b.z) | ((unsigned)f2bf(b.w) << 16);
  *(uint4*)(out + i) = pk;
}

// -------- transpose fp32 W[KD][ND] -> bf16 WT[ND][KD] (tiled 64x64) --------
template<int KD, int ND>
__global__ __launch_bounds__(256) void transpose_bf16(const float* __restrict__ W,
                                                      u16* __restrict__ WT) {
  __shared__ float tile[64][65];
  const int c0 = blockIdx.x * 64;
  const int k0 = blockIdx.y * 64;
  const int t = threadIdx.x;
  const int lr = t >> 2;
  const int lc = (t & 3) * 16;
  const float* src = W + (size_t)(k0 + lr) * ND + c0 + lc;
#pragma unroll
  for (int i = 0; i < 16; i += 4) {
    float4 v = *(const float4*)(src + i);
    tile[lr][lc + i] = v.x; tile[lr][lc + i + 1] = v.y;
    tile[lr][lc + i + 2] = v.z; tile[lr][lc + i + 3] = v.w;
  }
  __syncthreads();
  unsigned pk[8];
#pragma unroll
  for (int j = 0; j < 8; ++j) {
    u16 lo = f2bf(tile[lc + 2 * j][lr]);
    u16 hi = f2bf(tile[lc + 2 * j + 1][lr]);
    pk[j] = lo | ((unsigned)hi << 16);
  }
  u16* dst = WT + (size_t)(c0 + lr) * KD + k0 + lc;
  *(uint4*)(dst) = make_uint4(pk[0], pk[1], pk[2], pk[3]);
  *(uint4*)(dst + 8) = make_uint4(pk[4], pk[5], pk[6], pk[7]);
}

// -------- GEMM: C[M,N] = A[M,1024] * Bt[N,1024]^T + bias --------
// MODE 0: scatter to q/k (bf16 [bh][t][64]) and V TRANSPOSED ([bh][d][t]);
// MODE 1: fp32 out [M][NSIZE]
template<int NSIZE, int MODE>
__global__ __launch_bounds__(256) void gemm_bt(const u16* __restrict__ A,
                                               const u16* __restrict__ Bt,
                                               const float* __restrict__ bias,
                                               u16* __restrict__ qb,
                                               u16* __restrict__ kb,
                                               u16* __restrict__ vb,
                                               float* __restrict__ outp) {
  constexpr int K = 1024;
  __shared__ u16 As[128 * 64];
  __shared__ u16 Bs[128 * 64];
  const int tid = threadIdx.x;
  const int lane = tid & 63;
  const int wid = tid >> 6;
  const int wm = (wid >> 1) * 64;
  const int wn = (wid & 1) * 64;
  const int row0 = blockIdx.x * 128;
  const int col0 = blockIdx.y * 128;

  f32x4 acc[4][4] = {};

  const u16* ga = A + (size_t)(row0 + (tid >> 3)) * K + (tid & 7) * 8;
  const u16* gb = Bt + (size_t)(col0 + (tid >> 3)) * K + (tid & 7) * 8;
  u16* la = As + tid * 8;
  u16* lb = Bs + tid * 8;

  for (int kt = 0; kt < K / 64; ++kt) {
#pragma unroll
    for (int i = 0; i < 4; ++i) {
      gload_lds16(ga + (size_t)i * 32 * K + kt * 64, la + i * 2048);
      gload_lds16(gb + (size_t)i * 32 * K + kt * 64, lb + i * 2048);
    }
    __syncthreads();
#pragma unroll
    for (int ks = 0; ks < 2; ++ks) {
      short8 af[4], bf[4];
      const int ko = ks * 32 + (lane >> 4) * 8;
#pragma unroll
      for (int mt = 0; mt < 4; ++mt)
        af[mt] = *(const short8*)(As + (wm + mt * 16 + (lane & 15)) * 64 + ko);
#pragma unroll
      for (int nt = 0; nt < 4; ++nt)
        bf[nt] = *(const short8*)(Bs + (wn + nt * 16 + (lane & 15)) * 64 + ko);
#pragma unroll
      for (int mt = 0; mt < 4; ++mt)
#pragma unroll
        for (int nt = 0; nt < 4; ++nt)
          acc[mt][nt] = __builtin_amdgcn_mfma_f32_16x16x32_bf16(af[mt], bf[nt], acc[mt][nt], 0, 0, 0);
    }
    __syncthreads();
  }

#pragma unroll
  for (int nt = 0; nt < 4; ++nt) {
    const int col = col0 + wn + nt * 16 + (lane & 15);
    const float bv = bias[col];
    if (MODE == 0) {
      const int part = col >> 10;
      const int h = (col >> 6) & 15;
      const int d = col & 63;
      u16* dp = part == 0 ? qb : kb;
#pragma unroll
      for (int mt = 0; mt < 4; ++mt) {
#pragma unroll
        for (int r = 0; r < 4; ++r) {
          const int row = row0 + wm + mt * 16 + (lane >> 4) * 4 + r;
          const int bidx = row >> 11;
          const int tt = row & 2047;
          const u16 val = f2bf(acc[mt][nt][r] + bv);
          if (part == 2)
            vb[((size_t)((bidx << 4) + h) * 64 + d) * 2048 + tt] = val;
          else
            dp[((size_t)((bidx << 4) + h) * 2048 + tt) * 64 + d] = val;
        }
      }
    } else {
#pragma unroll
      for (int mt = 0; mt < 4; ++mt) {
#pragma unroll
        for (int r = 0; r < 4; ++r) {
          const int row = row0 + wm + mt * 16 + (lane >> 4) * 4 + r;
          outp[(size_t)row * NSIZE + col] = acc[mt][nt][r] + bv;
        }
      }
    }
  }
}

// -------- flash attention: 4 waves, 64 q-rows/block, 1024 blocks --------
// grid (32, 32): 4 blocks resident per CU (16 waves/CU). The blockIdx->q-tile
// map is phase-mixed so that under stride-256 round-robin placement each CU's
// 4 resident blocks sum to exactly 66 kv-iters: kq = bh>>3 picks phase
// {tb, 31-tb, tb+16, 31-(tb+16)}, bijective in (bh, T).
// K staged [t][64], V staged pre-transposed [d][t]; both XOR-swizzled.
// Double-buffered with raw s_barrier + counted vmcnt(4).
__global__ __launch_bounds__(256, 4) void attn_fwd(const u16* __restrict__ Qb,
                                                   const u16* __restrict__ Kb,
                                                   const u16* __restrict__ Vtb,
                                                   u16* __restrict__ Yb) {
  __shared__ u16 Ks[2][64 * 64];
  __shared__ u16 Vs[2][64 * 64];
  __shared__ u16 Ps[4][1024];
  const int bh = blockIdx.y;
  const int kq = bh >> 3;
  int tb = ((int)blockIdx.x + ((kq >> 1) << 4)) & 31;
  const int T = (kq & 1) ? (31 - tb) : tb;
  const int q0 = T * 64;
  const int tid = threadIdx.x;
  const int lane = tid & 63;
  const int wid = tid >> 6;
  const int l15 = lane & 15;
  const int g4 = lane >> 4;
  const size_t bhq = (size_t)bh * 2048 * 64;
  const u16* Kbase = Kb + bhq;
  const u16* Vbase = Vtb + bhq;  // [64 d][2048 t] per bh
  const float C2 = 0.18033688011112042f;  // 0.125 * log2(e)
  u16* Pw = &Ps[wid][0];
  const int wrow0 = q0 + wid * 16;
  const int nkv = T + 1;

  short8 qf[2];
  {
    const u16* qp = Qb + bhq + (size_t)(wrow0 + l15) * 64 + g4 * 8;
    qf[0] = *(const short8*)(qp);
    qf[1] = *(const short8*)(qp + 32);
  }
  f32x4 accy[4] = {};
  float m_run[4] = {-1e30f, -1e30f, -1e30f, -1e30f};
  float l_run[4] = {0.f, 0.f, 0.f, 0.f};

  int cur = 0;
  // prologue: stage kv-tile 0 into buf 0 (2 chunks per thread per matrix)
#pragma unroll
  for (int cc = 0; cc < 2; ++cc) {
    const int c = tid + cc * 256;
    const int srow = c >> 3;
    const int sblk = (c & 7) ^ (srow & 7);
    gload_lds16(Kbase + srow * 64 + sblk * 8, Ks[0] + c * 8);
    gload_lds16(Vbase + (size_t)srow * 2048 + sblk * 8, Vs[0] + c * 8);
  }

  for (int kv = 0; kv < nkv; ++kv) {
    const int kv0 = kv * 64;
    if (kv + 1 < nkv) {
      const int nx0 = kv0 + 64;
#pragma unroll
      for (int cc = 0; cc < 2; ++cc) {
        const int c = tid + cc * 256;
        const int srow = c >> 3;
        const int sblk = (c & 7) ^ (srow & 7);
        gload_lds16(Kbase + (size_t)(nx0 + srow) * 64 + sblk * 8, Ks[cur ^ 1] + c * 8);
        gload_lds16(Vbase + (size_t)srow * 2048 + nx0 + sblk * 8, Vs[cur ^ 1] + c * 8);
      }
      asm volatile("s_waitcnt vmcnt(4)" ::: "memory");
    } else {
      asm volatile("s_waitcnt vmcnt(0)" ::: "memory");
    }
    __builtin_amdgcn_s_barrier();
    asm volatile("" ::: "memory");

    const u16* Kt = Ks[cur];
    const u16* Vt = Vs[cur];
    // ---- S = Q K^T (swizzled b128 reads of K rows) ----
    f32x4 s[4];
#pragma unroll
    for (int nt = 0; nt < 4; ++nt) {
      f32x4 z = {};
#pragma unroll
      for (int ks = 0; ks < 2; ++ks) {
        const int R = nt * 16 + l15;
        const int B = ks * 64 + g4 * 16;
        short8 kf = *(const short8*)((const char*)Kt + R * 128 + (B ^ ((R & 7) << 4)));
        z = __builtin_amdgcn_mfma_f32_16x16x32_bf16(qf[ks], kf, z, 0, 0, 0);
      }
      s[nt] = z;
    }

    // ---- causal mask (diagonal tile only) ----
    if (kv0 + 63 > wrow0) {
      const int rowb = wrow0 + g4 * 4;
#pragma unroll
      for (int nt = 0; nt < 4; ++nt) {
        const int colg = kv0 + nt * 16 + l15;
#pragma unroll
        for (int r = 0; r < 4; ++r)
          if (colg > rowb + r) s[nt][r] = -1e30f;
      }
    }

    // ---- online softmax (exp2 domain) ----
#pragma unroll
    for (int r = 0; r < 4; ++r) {
      float mx = fmaxf(fmaxf(s[0][r], s[1][r]), fmaxf(s[2][r], s[3][r]));
      mx = fmaxf(mx, __shfl_xor(mx, 1));
      mx = fmaxf(mx, __shfl_xor(mx, 2));
      mx = fmaxf(mx, __shfl_xor(mx, 4));
      mx = fmaxf(mx, __shfl_xor(mx, 8));
      const float mnew = fmaxf(m_run[r], mx);
      const float m2 = mnew * C2;
      const float alpha = __builtin_amdgcn_exp2f(fmaf(m_run[r], C2, -m2));
      float ps = 0.f;
#pragma unroll
      for (int nt = 0; nt < 4; ++nt) {
        const float p = __builtin_amdgcn_exp2f(fmaf(s[nt][r], C2, -m2));
        s[nt][r] = p;
        ps += p;
      }
      ps += __shfl_xor(ps, 1);
      ps += __shfl_xor(ps, 2);
      ps += __shfl_xor(ps, 4);
      ps += __shfl_xor(ps, 8);
      l_run[r] = l_run[r] * alpha + ps;
      m_run[r] = mnew;
#pragma unroll
      for (int nt = 0; nt < 4; ++nt) accy[nt][r] *= alpha;
    }

    // ---- P -> per-wave LDS (swizzled), then PV ----
#pragma unroll
    for (int nt = 0; nt < 4; ++nt) {
      const int colB = (nt * 16 + l15) * 2;
#pragma unroll
      for (int r = 0; r < 4; ++r) {
        const int rowL = g4 * 4 + r;
        *(u16*)((char*)Pw + rowL * 128 + (colB ^ ((rowL & 7) << 4))) = f2bf(s[nt][r]);
      }
    }
#pragma unroll
    for (int ks = 0; ks < 2; ++ks) {
      const int B = ks * 64 + g4 * 16;
      short8 pf = *(const short8*)((const char*)Pw + l15 * 128 + (B ^ ((l15 & 7) << 4)));
#pragma unroll
      for (int nt = 0; nt < 4; ++nt) {
        const int R = nt * 16 + l15;
        short8 vf = *(const short8*)((const char*)Vt + R * 128 + (B ^ ((R & 7) << 4)));
        accy[nt] = __builtin_amdgcn_mfma_f32_16x16x32_bf16(pf, vf, accy[nt], 0, 0, 0);
      }
    }

    asm volatile("" ::: "memory");
    __builtin_amdgcn_s_barrier();
    cur ^= 1;
  }

  // ---- epilogue: normalize, write y [b][t][h*64+d] bf16 ----
#pragma unroll
  for (int r = 0; r < 4; ++r) {
    const int row = wrow0 + g4 * 4 + r;
    const float inv = 1.0f / l_run[r];
    const size_t base = ((size_t)(bh >> 4) * 2048 + row) * 1024 + (bh & 15) * 64;
#pragma unroll
    for (int nt = 0; nt < 4; ++nt)
      Yb[base + nt * 16 + l15] = f2bf(accy[nt][r] * inv);
  }
}

extern "C" void kernel_launch(void* const* d_in, const int* in_sizes, int n_in,
                              void* d_out, int out_size, void* d_ws, size_t ws_size,
                              hipStream_t stream) {
  const float* x      = (const float*)d_in[0];
  const float* w_attn = (const float*)d_in[1];
  const float* b_attn = (const float*)d_in[2];
  const float* w_proj = (const float*)d_in[3];
  const float* b_proj = (const float*)d_in[4];
  float* out = (float*)d_out;
  char* ws = (char*)d_ws;

  u16* xb  = (u16*)(ws + (size_t)0);           // 8 MB: x bf16 [4096][1024]
  u16* wTa = (u16*)(ws + ((size_t)8  << 20));  // 6 MB: w_attn^T bf16 [3072][1024]
  u16* wTp = (u16*)(ws + ((size_t)14 << 20));  // 2 MB: w_proj^T bf16 [1024][1024]
  u16* qb  = (u16*)(ws + ((size_t)16 << 20));  // 8 MB: Q [32][2048][64]
  u16* kb  = (u16*)(ws + ((size_t)24 << 20));  // 8 MB: K [32][2048][64]
  u16* vb  = (u16*)(ws + ((size_t)32 << 20));  // 8 MB: V^T [32][64][2048]
  u16* yb  = (u16*)(ws + ((size_t)40 << 20));  // 8 MB: y bf16 [4096][1024]

  cvt_bf16<<<2048, 256, 0, stream>>>(x, xb, 2 * 2048 * 1024);
  transpose_bf16<1024, 3072><<<dim3(48, 16), 256, 0, stream>>>(w_attn, wTa);
  transpose_bf16<1024, 1024><<<dim3(16, 16), 256, 0, stream>>>(w_proj, wTp);
  gemm_bt<3072, 0><<<dim3(32, 24), 256, 0, stream>>>(xb, wTa, b_attn, qb, kb, vb, nullptr);
  attn_fwd<<<dim3(32, 32), 256, 0, stream>>>(qb, kb, vb, yb);
  gemm_bt<1024, 1><<<dim3(32, 8), 256, 0, stream>>>(yb, wTp, b_proj, nullptr, nullptr, nullptr, out);
}

// Round 5
// 133.171 us; speedup vs baseline: 1.9519x; 1.1290x over previous
//
#include <hip/hip_runtime.h>
#include <hip/hip_bf16.h>
#include <math.h>

typedef __attribute__((ext_vector_type(8))) short short8;
typedef __attribute__((ext_vector_type(4))) float f32x4;
typedef unsigned short u16;

static __device__ __forceinline__ u16 f2bf(float f) {
  union { float f; unsigned u; } v; v.f = f;
  unsigned r = v.u + 0x7fffu + ((v.u >> 16) & 1u);
  return (u16)(r >> 16);
}

static __device__ __forceinline__ void gload_lds16(const void* g, void* l) {
  __builtin_amdgcn_global_load_lds(
      (const __attribute__((address_space(1))) void*)g,
      (__attribute__((address_space(3))) void*)l, 16, 0, 0);
}

// ---------------- fp32 -> bf16 convert (8 elems/thread) ----------------
__global__ __launch_bounds__(256) void cvt_bf16(const float* __restrict__ in,
                                                u16* __restrict__ out, int n) {
  int i = (blockIdx.x * 256 + threadIdx.x) * 8;
  if (i >= n) return;
  float4 a = *(const float4*)(in + i);
  float4 b = *(const float4*)(in + i + 4);
  uint4 pk;
  pk.x = f2bf(a.x) | ((unsigned)f2bf(a.y) << 16);
  pk.y = f2bf(a.z) | ((unsigned)f2bf(a.w) << 16);
  pk.z = f2bf(b.x) | ((unsigned)f2bf(b.y) << 16);
  pk.w = f2bf(b.z) | ((unsigned)f2bf(b.w) << 16);
  *(uint4*)(out + i) = pk;
}

// -------- transpose fp32 W[KD][ND] -> bf16 WT[ND][KD] (tiled 64x64) --------
template<int KD, int ND>
__global__ __launch_bounds__(256) void transpose_bf16(const float* __restrict__ W,
                                                      u16* __restrict__ WT) {
  __shared__ float tile[64][65];
  const int c0 = blockIdx.x * 64;
  const int k0 = blockIdx.y * 64;
  const int t = threadIdx.x;
  const int lr = t >> 2;
  const int lc = (t & 3) * 16;
  const float* src = W + (size_t)(k0 + lr) * ND + c0 + lc;
#pragma unroll
  for (int i = 0; i < 16; i += 4) {
    float4 v = *(const float4*)(src + i);
    tile[lr][lc + i] = v.x; tile[lr][lc + i + 1] = v.y;
    tile[lr][lc + i + 2] = v.z; tile[lr][lc + i + 3] = v.w;
  }
  __syncthreads();
  unsigned pk[8];
#pragma unroll
  for (int j = 0; j < 8; ++j) {
    u16 lo = f2bf(tile[lc + 2 * j][lr]);
    u16 hi = f2bf(tile[lc + 2 * j + 1][lr]);
    pk[j] = lo | ((unsigned)hi << 16);
  }
  u16* dst = WT + (size_t)(c0 + lr) * KD + k0 + lc;
  *(uint4*)(dst) = make_uint4(pk[0], pk[1], pk[2], pk[3]);
  *(uint4*)(dst + 8) = make_uint4(pk[4], pk[5], pk[6], pk[7]);
}

// -------- GEMM: C[M,N] = A[M,1024] * Bt[N,1024]^T + bias --------
// MODE 0: scatter to q/k (bf16 [bh][t][64]) and V TRANSPOSED ([bh][d][t]);
// MODE 1: fp32 out [M][NSIZE]
template<int NSIZE, int MODE>
__global__ __launch_bounds__(256) void gemm_bt(const u16* __restrict__ A,
                                               const u16* __restrict__ Bt,
                                               const float* __restrict__ bias,
                                               u16* __restrict__ qb,
                                               u16* __restrict__ kb,
                                               u16* __restrict__ vb,
                                               float* __restrict__ outp) {
  constexpr int K = 1024;
  __shared__ u16 As[128 * 64];
  __shared__ u16 Bs[128 * 64];
  const int tid = threadIdx.x;
  const int lane = tid & 63;
  const int wid = tid >> 6;
  const int wm = (wid >> 1) * 64;
  const int wn = (wid & 1) * 64;
  const int row0 = blockIdx.x * 128;
  const int col0 = blockIdx.y * 128;

  f32x4 acc[4][4] = {};

  const u16* ga = A + (size_t)(row0 + (tid >> 3)) * K + (tid & 7) * 8;
  const u16* gb = Bt + (size_t)(col0 + (tid >> 3)) * K + (tid & 7) * 8;
  u16* la = As + tid * 8;
  u16* lb = Bs + tid * 8;

  for (int kt = 0; kt < K / 64; ++kt) {
#pragma unroll
    for (int i = 0; i < 4; ++i) {
      gload_lds16(ga + (size_t)i * 32 * K + kt * 64, la + i * 2048);
      gload_lds16(gb + (size_t)i * 32 * K + kt * 64, lb + i * 2048);
    }
    __syncthreads();
#pragma unroll
    for (int ks = 0; ks < 2; ++ks) {
      short8 af[4], bf[4];
      const int ko = ks * 32 + (lane >> 4) * 8;
#pragma unroll
      for (int mt = 0; mt < 4; ++mt)
        af[mt] = *(const short8*)(As + (wm + mt * 16 + (lane & 15)) * 64 + ko);
#pragma unroll
      for (int nt = 0; nt < 4; ++nt)
        bf[nt] = *(const short8*)(Bs + (wn + nt * 16 + (lane & 15)) * 64 + ko);
#pragma unroll
      for (int mt = 0; mt < 4; ++mt)
#pragma unroll
        for (int nt = 0; nt < 4; ++nt)
          acc[mt][nt] = __builtin_amdgcn_mfma_f32_16x16x32_bf16(af[mt], bf[nt], acc[mt][nt], 0, 0, 0);
    }
    __syncthreads();
  }

#pragma unroll
  for (int nt = 0; nt < 4; ++nt) {
    const int col = col0 + wn + nt * 16 + (lane & 15);
    const float bv = bias[col];
    if (MODE == 0) {
      const int part = col >> 10;
      const int h = (col >> 6) & 15;
      const int d = col & 63;
      u16* dp = part == 0 ? qb : kb;
#pragma unroll
      for (int mt = 0; mt < 4; ++mt) {
#pragma unroll
        for (int r = 0; r < 4; ++r) {
          const int row = row0 + wm + mt * 16 + (lane >> 4) * 4 + r;
          const int bidx = row >> 11;
          const int tt = row & 2047;
          const u16 val = f2bf(acc[mt][nt][r] + bv);
          if (part == 2)
            vb[((size_t)((bidx << 4) + h) * 64 + d) * 2048 + tt] = val;
          else
            dp[((size_t)((bidx << 4) + h) * 2048 + tt) * 64 + d] = val;
        }
      }
    } else {
#pragma unroll
      for (int mt = 0; mt < 4; ++mt) {
#pragma unroll
        for (int r = 0; r < 4; ++r) {
          const int row = row0 + wm + mt * 16 + (lane >> 4) * 4 + r;
          outp[(size_t)row * NSIZE + col] = acc[mt][nt][r] + bv;
        }
      }
    }
  }
}

// -------- flash attention: swapped-QK^T, in-lane softmax (DS-pipe diet) ----
// grid (32, 32): phase-mixed blockIdx->q-tile map (each CU's resident set is
// balanced). S^T = mfma(K, Q): lane l15 owns q-row l15's 16 scores -> row-max
// is an in-register tree + 2 shuffles; row-sum via ones-MFMA lands directly
// in accumulator layout; P packed to 4x ds_write_b64.
// DS ops/wave-iter: 74 -> 28 (the R2-R4 invariant ~75us was DS-pipe-bound).
__global__ __launch_bounds__(256, 4) void attn_fwd(const u16* __restrict__ Qb,
                                                   const u16* __restrict__ Kb,
                                                   const u16* __restrict__ Vtb,
                                                   u16* __restrict__ Yb) {
  __shared__ u16 Ks[2][64 * 64];
  __shared__ u16 Vs[2][64 * 64];
  __shared__ u16 Ps[4][1024];
  const int bh = blockIdx.y;
  const int kq = bh >> 3;
  int tb = ((int)blockIdx.x + ((kq >> 1) << 4)) & 31;
  const int T = (kq & 1) ? (31 - tb) : tb;
  const int q0 = T * 64;
  const int tid = threadIdx.x;
  const int lane = tid & 63;
  const int wid = tid >> 6;
  const int l15 = lane & 15;
  const int g4 = lane >> 4;
  const size_t bhq = (size_t)bh * 2048 * 64;
  const u16* Kbase = Kb + bhq;
  const u16* Vbase = Vtb + bhq;  // [64 d][2048 t] per bh
  const float C2 = 0.18033688011112042f;  // 0.125 * log2(e)
  u16* Pw = &Ps[wid][0];
  const int wrow0 = q0 + wid * 16;
  const int nkv = T + 1;

  short8 ones;
#pragma unroll
  for (int i = 0; i < 8; ++i) ones[i] = (short)0x3F80;  // bf16 1.0

  short8 qf[2];
  {
    const u16* qp = Qb + bhq + (size_t)(wrow0 + l15) * 64 + g4 * 8;
    qf[0] = *(const short8*)(qp);
    qf[1] = *(const short8*)(qp + 32);
  }
  f32x4 accy[4] = {};
  float m_q = -1e30f;              // running max for q = l15 (uniform over g4)
  float m_r[4] = {-1e30f, -1e30f, -1e30f, -1e30f};  // accy-layout copy
  float l_r[4] = {0.f, 0.f, 0.f, 0.f};              // running sum, accy layout

  int cur = 0;
#pragma unroll
  for (int cc = 0; cc < 2; ++cc) {
    const int c = tid + cc * 256;
    const int srow = c >> 3;
    const int sblk = (c & 7) ^ (srow & 7);
    gload_lds16(Kbase + srow * 64 + sblk * 8, Ks[0] + c * 8);
    gload_lds16(Vbase + (size_t)srow * 2048 + sblk * 8, Vs[0] + c * 8);
  }

  for (int kv = 0; kv < nkv; ++kv) {
    const int kv0 = kv * 64;
    if (kv + 1 < nkv) {
      const int nx0 = kv0 + 64;
#pragma unroll
      for (int cc = 0; cc < 2; ++cc) {
        const int c = tid + cc * 256;
        const int srow = c >> 3;
        const int sblk = (c & 7) ^ (srow & 7);
        gload_lds16(Kbase + (size_t)(nx0 + srow) * 64 + sblk * 8, Ks[cur ^ 1] + c * 8);
        gload_lds16(Vbase + (size_t)srow * 2048 + nx0 + sblk * 8, Vs[cur ^ 1] + c * 8);
      }
      asm volatile("s_waitcnt vmcnt(4)" ::: "memory");
    } else {
      asm volatile("s_waitcnt vmcnt(0)" ::: "memory");
    }
    __builtin_amdgcn_s_barrier();
    asm volatile("" ::: "memory");

    const u16* Kt = Ks[cur];
    const u16* Vt = Vs[cur];
    // ---- S^T = K Q^T : s[nt][r] = S[q=l15][k = kv0 + nt*16 + g4*4 + r] ----
    f32x4 s[4];
#pragma unroll
    for (int nt = 0; nt < 4; ++nt) {
      f32x4 z = {};
#pragma unroll
      for (int ks = 0; ks < 2; ++ks) {
        const int R = nt * 16 + l15;
        const int B = ks * 64 + g4 * 16;
        short8 kf = *(const short8*)((const char*)Kt + R * 128 + (B ^ ((R & 7) << 4)));
        z = __builtin_amdgcn_mfma_f32_16x16x32_bf16(kf, qf[ks], z, 0, 0, 0);
      }
      s[nt] = z;
    }

    // ---- causal mask (diagonal-straddling tiles only) ----
    if (kv0 + 63 > wrow0) {
      const int qg = wrow0 + l15;
#pragma unroll
      for (int nt = 0; nt < 4; ++nt) {
        const int kbase = kv0 + nt * 16 + g4 * 4;
#pragma unroll
        for (int r = 0; r < 4; ++r)
          if (kbase + r > qg) s[nt][r] = -1e30f;
      }
    }

    // ---- in-lane row max (tree) + 2-shuffle butterfly over g4 ----
    f32x4 mt4;
#pragma unroll
    for (int r = 0; r < 4; ++r)
      mt4[r] = fmaxf(fmaxf(s[0][r], s[1][r]), fmaxf(s[2][r], s[3][r]));
    float mx = fmaxf(fmaxf(mt4[0], mt4[1]), fmaxf(mt4[2], mt4[3]));
    mx = fmaxf(mx, __shfl_xor(mx, 16));
    mx = fmaxf(mx, __shfl_xor(mx, 32));
    const float mnew = fmaxf(m_q, mx);
    const float m2 = mnew * C2;
#pragma unroll
    for (int nt = 0; nt < 4; ++nt)
#pragma unroll
      for (int r = 0; r < 4; ++r)
        s[nt][r] = __builtin_amdgcn_exp2f(fmaf(s[nt][r], C2, -m2));
    m_q = mnew;

    // ---- redistribute new max to accy layout (q = g4*4 + rr), rescale ----
    float alpha_r[4];
#pragma unroll
    for (int rr = 0; rr < 4; ++rr) {
      const float mn = __shfl(mnew, g4 * 4 + rr);
      alpha_r[rr] = __builtin_amdgcn_exp2f((m_r[rr] - mn) * C2);
      m_r[rr] = mn;
    }
#pragma unroll
    for (int nt = 0; nt < 4; ++nt)
#pragma unroll
      for (int rr = 0; rr < 4; ++rr) accy[nt][rr] *= alpha_r[rr];

    // ---- P -> per-wave LDS (packed b64, swizzled) ----
#pragma unroll
    for (int nt = 0; nt < 4; ++nt) {
      const unsigned lo = f2bf(s[nt][0]) | ((unsigned)f2bf(s[nt][1]) << 16);
      const unsigned hi = f2bf(s[nt][2]) | ((unsigned)f2bf(s[nt][3]) << 16);
      const int colB = nt * 32 + g4 * 8;
      *(uint2*)((char*)Pw + l15 * 128 + (colB ^ ((l15 & 7) << 4))) = make_uint2(lo, hi);
    }

    // ---- read P fragments, row-sums via ones-MFMA, PV ----
    short8 pf[2];
#pragma unroll
    for (int ks = 0; ks < 2; ++ks) {
      const int B = ks * 64 + g4 * 16;
      pf[ks] = *(const short8*)((const char*)Pw + l15 * 128 + (B ^ ((l15 & 7) << 4)));
    }
    f32x4 psum = {};
    psum = __builtin_amdgcn_mfma_f32_16x16x32_bf16(pf[0], ones, psum, 0, 0, 0);
    psum = __builtin_amdgcn_mfma_f32_16x16x32_bf16(pf[1], ones, psum, 0, 0, 0);
#pragma unroll
    for (int rr = 0; rr < 4; ++rr) l_r[rr] = l_r[rr] * alpha_r[rr] + psum[rr];

#pragma unroll
    for (int ks = 0; ks < 2; ++ks) {
#pragma unroll
      for (int nt = 0; nt < 4; ++nt) {
        const int R = nt * 16 + l15;
        const int B = ks * 64 + g4 * 16;
        short8 vf = *(const short8*)((const char*)Vt + R * 128 + (B ^ ((R & 7) << 4)));
        accy[nt] = __builtin_amdgcn_mfma_f32_16x16x32_bf16(pf[ks], vf, accy[nt], 0, 0, 0);
      }
    }

    asm volatile("" ::: "memory");
    __builtin_amdgcn_s_barrier();
    cur ^= 1;
  }

  // ---- epilogue: normalize (l already in accy layout), write y bf16 ----
#pragma unroll
  for (int r = 0; r < 4; ++r) {
    const int row = wrow0 + g4 * 4 + r;
    const float inv = 1.0f / l_r[r];
    const size_t base = ((size_t)(bh >> 4) * 2048 + row) * 1024 + (bh & 15) * 64;
#pragma unroll
    for (int nt = 0; nt < 4; ++nt)
      Yb[base + nt * 16 + l15] = f2bf(accy[nt][r] * inv);
  }
}

extern "C" void kernel_launch(void* const* d_in, const int* in_sizes, int n_in,
                              void* d_out, int out_size, void* d_ws, size_t ws_size,
                              hipStream_t stream) {
  const float* x      = (const float*)d_in[0];
  const float* w_attn = (const float*)d_in[1];
  const float* b_attn = (const float*)d_in[2];
  const float* w_proj = (const float*)d_in[3];
  const float* b_proj = (const float*)d_in[4];
  float* out = (float*)d_out;
  char* ws = (char*)d_ws;

  u16* xb  = (u16*)(ws + (size_t)0);           // 8 MB: x bf16 [4096][1024]
  u16* wTa = (u16*)(ws + ((size_t)8  << 20));  // 6 MB: w_attn^T bf16 [3072][1024]
  u16* wTp = (u16*)(ws + ((size_t)14 << 20));  // 2 MB: w_proj^T bf16 [1024][1024]
  u16* qb  = (u16*)(ws + ((size_t)16 << 20));  // 8 MB: Q [32][2048][64]
  u16* kb  = (u16*)(ws + ((size_t)24 << 20));  // 8 MB: K [32][2048][64]
  u16* vb  = (u16*)(ws + ((size_t)32 << 20));  // 8 MB: V^T [32][64][2048]
  u16* yb  = (u16*)(ws + ((size_t)40 << 20));  // 8 MB: y bf16 [4096][1024]

  cvt_bf16<<<2048, 256, 0, stream>>>(x, xb, 2 * 2048 * 1024);
  transpose_bf16<1024, 3072><<<dim3(48, 16), 256, 0, stream>>>(w_attn, wTa);
  transpose_bf16<1024, 1024><<<dim3(16, 16), 256, 0, stream>>>(w_proj, wTp);
  gemm_bt<3072, 0><<<dim3(32, 24), 256, 0, stream>>>(xb, wTa, b_attn, qb, kb, vb, nullptr);
  attn_fwd<<<dim3(32, 32), 256, 0, stream>>>(qb, kb, vb, yb);
  gemm_bt<1024, 1><<<dim3(32, 8), 256, 0, stream>>>(yb, wTp, b_proj, nullptr, nullptr, nullptr, out);
}